// Round 5
// baseline (652.699 us; speedup 1.0000x reference)
//
#include <hip/hip_runtime.h>
#include <cstdint>
#include <cstddef>

typedef unsigned short u16;
typedef float f32x4 __attribute__((ext_vector_type(4)));
typedef short short8 __attribute__((ext_vector_type(8)));
typedef int i32x4 __attribute__((ext_vector_type(4)));

// ---------------- helpers ----------------

__device__ __forceinline__ float geluf(float v) {
  return 0.5f * v * (1.0f + erff(v * 0.70710678118654752440f));
}

__device__ __forceinline__ u16 f2bf(float f) {  // RNE fp32 -> bf16 bits
  unsigned u = __float_as_uint(f);
  u = (u + 0x7FFFu + ((u >> 16) & 1u)) >> 16;
  return (u16)u;
}

__device__ __forceinline__ void waveRed2(float& s, float& s2) {
#pragma unroll
  for (int m = 1; m < 64; m <<= 1) {
    s += __shfl_xor(s, m);
    s2 += __shfl_xor(s2, m);
  }
}

// ---------------- LN over 512 (router input) ----------------
__global__ __launch_bounds__(256) void k_ln512(const float* __restrict__ x,
                                               const float* __restrict__ g,
                                               const float* __restrict__ b,
                                               float* __restrict__ out) {
  __shared__ float red[8];
  const int t = blockIdx.x, tid = threadIdx.x;
  const float v0 = x[(size_t)t * 512 + tid];
  const float v1 = x[(size_t)t * 512 + 256 + tid];
  float s = v0 + v1, s2 = v0 * v0 + v1 * v1;
  waveRed2(s, s2);
  if ((tid & 63) == 0) { red[(tid >> 6) * 2] = s; red[(tid >> 6) * 2 + 1] = s2; }
  __syncthreads();
  s = red[0] + red[2] + red[4] + red[6];
  s2 = red[1] + red[3] + red[5] + red[7];
  const float mu = s * (1.f / 512.f);
  const float var = fmaxf(s2 * (1.f / 512.f) - mu * mu, 0.f);
  const float rstd = 1.f / sqrtf(var + 1e-5f);
  out[(size_t)t * 512 + tid] = (v0 - mu) * rstd * g[tid] + b[tid];
  out[(size_t)t * 512 + 256 + tid] = (v1 - mu) * rstd * g[tid + 256] + b[tid + 256];
}

// ---------------- nvphi precompute: [2048,256] = nv@pW1[:128] + pb1 ----------------
__global__ __launch_bounds__(256) void k_nvphi(const float* __restrict__ nv,
                                               const float* __restrict__ pW1,
                                               const float* __restrict__ pb1,
                                               float* __restrict__ nvphi) {
  __shared__ float nvs[128];
  const int n = blockIdx.x, tid = threadIdx.x;
  if (tid < 128) nvs[tid] = nv[n * 128 + tid];
  __syncthreads();
  float s = pb1[tid];
#pragma unroll 4
  for (int i = 0; i < 128; ++i) s = fmaf(nvs[i], pW1[i * 256 + tid], s);
  nvphi[n * 256 + tid] = s;
}

// ---------------- pW2T[n][k] = bf16(pW2[k][n]) ----------------
__global__ __launch_bounds__(256) void k_pw2t(const float* __restrict__ pW2,
                                              u16* __restrict__ pW2T) {
  const int n = blockIdx.x, k = threadIdx.x;
  pW2T[n * 256 + k] = f2bf(pW2[k * 256 + n]);
}

// ---------------- tiled fp32 GEMM, C = act(A[M,K] @ B[N,K]^T) ----------------
template <bool GELU_>
__global__ __launch_bounds__(256) void gemm_bt(const float* __restrict__ A,
                                               const float* __restrict__ B,
                                               float* __restrict__ C, int M, int N,
                                               int K) {
  __shared__ float As[16][68];
  __shared__ float Bs[16][68];
  const int tid = threadIdx.x;
  const int tn = tid & 15, tm = tid >> 4;
  const int m0 = blockIdx.y * 64, n0 = blockIdx.x * 64;
  const int lr = tid >> 2, lk = (tid & 3) << 2;
  float acc[4][4] = {};
  for (int k0 = 0; k0 < K; k0 += 16) {
    const float4 av = *(const float4*)&A[(size_t)(m0 + lr) * K + k0 + lk];
    const float4 bv = *(const float4*)&B[(size_t)(n0 + lr) * K + k0 + lk];
    As[lk + 0][lr] = av.x; As[lk + 1][lr] = av.y; As[lk + 2][lr] = av.z; As[lk + 3][lr] = av.w;
    Bs[lk + 0][lr] = bv.x; Bs[lk + 1][lr] = bv.y; Bs[lk + 2][lr] = bv.z; Bs[lk + 3][lr] = bv.w;
    __syncthreads();
#pragma unroll
    for (int k = 0; k < 16; ++k) {
      float a[4], b[4];
      *(float4*)a = *(const float4*)&As[k][tm * 4];
      *(float4*)b = *(const float4*)&Bs[k][tn * 4];
#pragma unroll
      for (int i = 0; i < 4; ++i)
#pragma unroll
        for (int j = 0; j < 4; ++j) acc[i][j] = fmaf(a[i], b[j], acc[i][j]);
    }
    __syncthreads();
  }
#pragma unroll
  for (int i = 0; i < 4; ++i) {
    float4 v;
    float* vp = (float*)&v;
#pragma unroll
    for (int j = 0; j < 4; ++j) {
      float xv = acc[i][j];
      if (GELU_) xv = geluf(xv);
      vp[j] = xv;
    }
    *(float4*)&C[(size_t)(m0 + tm * 4 + i) * N + n0 + tn * 4] = v;
  }
}

// ---------------- tiled fp32 GEMM, C = act(A[M,K] @ B[K,N] + bias) ----------------
template <bool GELU_>
__global__ __launch_bounds__(256) void gemm_bn(const float* __restrict__ A,
                                               const float* __restrict__ B,
                                               const float* __restrict__ bias,
                                               float* __restrict__ C, int M, int N,
                                               int K) {
  __shared__ float As[16][68];
  __shared__ float Bs[16][68];
  const int tid = threadIdx.x;
  const int tn = tid & 15, tm = tid >> 4;
  const int m0 = blockIdx.y * 64, n0 = blockIdx.x * 64;
  const int lr = tid >> 2, lk = (tid & 3) << 2;
  const int bk = tid >> 4, bn = (tid & 15) << 2;
  float acc[4][4] = {};
  for (int k0 = 0; k0 < K; k0 += 16) {
    const float4 av = *(const float4*)&A[(size_t)(m0 + lr) * K + k0 + lk];
    const float4 bv = *(const float4*)&B[(size_t)(k0 + bk) * N + n0 + bn];
    As[lk + 0][lr] = av.x; As[lk + 1][lr] = av.y; As[lk + 2][lr] = av.z; As[lk + 3][lr] = av.w;
    *(float4*)&Bs[bk][bn] = bv;
    __syncthreads();
#pragma unroll
    for (int k = 0; k < 16; ++k) {
      float a[4], b[4];
      *(float4*)a = *(const float4*)&As[k][tm * 4];
      *(float4*)b = *(const float4*)&Bs[k][tn * 4];
#pragma unroll
      for (int i = 0; i < 4; ++i)
#pragma unroll
        for (int j = 0; j < 4; ++j) acc[i][j] = fmaf(a[i], b[j], acc[i][j]);
    }
    __syncthreads();
  }
#pragma unroll
  for (int i = 0; i < 4; ++i) {
    float4 v;
    float* vp = (float*)&v;
#pragma unroll
    for (int j = 0; j < 4; ++j) {
      float xv = acc[i][j] + bias[n0 + tn * 4 + j];
      if (GELU_) xv = geluf(xv);
      vp[j] = xv;
    }
    *(float4*)&C[(size_t)(m0 + tm * 4 + i) * N + n0 + tn * 4] = v;
  }
}

// ---------------- top-64 of 2048 scores per token ----------------
__global__ __launch_bounds__(256) void k_topk(const float* __restrict__ scores,
                                              int* __restrict__ idxout) {
  __shared__ int redc[4];
  __shared__ unsigned cg_cnt, ec;
  __shared__ int eqbuf[64];
  const int t = blockIdx.x, tid = threadIdx.x;
  unsigned key[8];
#pragma unroll
  for (int j = 0; j < 8; ++j) {
    const unsigned u = __float_as_uint(scores[(size_t)t * 2048 + tid + 256 * j]);
    key[j] = (u & 0x80000000u) ? ~u : (u | 0x80000000u);
  }
  unsigned lo = 0u, hi = 0xFFFFFFFFu;
  while (lo < hi) {
    const unsigned mid = (unsigned)(((unsigned long long)lo + hi + 1ull) >> 1);
    int c = 0;
#pragma unroll
    for (int j = 0; j < 8; ++j) c += (key[j] >= mid);
#pragma unroll
    for (int m = 1; m < 64; m <<= 1) c += __shfl_xor(c, m);
    if ((tid & 63) == 0) redc[tid >> 6] = c;
    __syncthreads();
    const int total = redc[0] + redc[1] + redc[2] + redc[3];
    __syncthreads();
    if (total >= 64) lo = mid; else hi = mid - 1;
  }
  if (tid == 0) { cg_cnt = 0u; ec = 0u; }
  __syncthreads();
#pragma unroll
  for (int j = 0; j < 8; ++j) {
    if (key[j] > lo) {
      const unsigned pos = atomicAdd(&cg_cnt, 1u);
      idxout[(size_t)t * 64 + pos] = tid + 256 * j;
    } else if (key[j] == lo) {
      const unsigned e = atomicAdd(&ec, 1u);
      if (e < 64u) eqbuf[e] = tid + 256 * j;
    }
  }
  __syncthreads();
  if (tid == 0) {
    const int cg = (int)cg_cnt;
    int ne = (int)ec; if (ne > 64) ne = 64;
    const int need = 64 - cg;
    for (int i = 1; i < ne; ++i) {
      const int v = eqbuf[i];
      int j = i - 1;
      while (j >= 0 && eqbuf[j] > v) { eqbuf[j + 1] = eqbuf[j]; --j; }
      eqbuf[j + 1] = v;
    }
    for (int i = 0; i < need; ++i) idxout[(size_t)t * 64 + cg + i] = eqbuf[i];
  }
}

// ---------------- act[t][k] = gelu(dot(x[t], W_in[idx[t][k]])) ----------------
__global__ __launch_bounds__(256) void k_act(const float* __restrict__ x,
                                             const float* __restrict__ W_in,
                                             const int* __restrict__ idx,
                                             float* __restrict__ act) {
  __shared__ float xs[512];
  const int t = blockIdx.x, tid = threadIdx.x;
  xs[tid] = x[(size_t)t * 512 + tid];
  xs[tid + 256] = x[(size_t)t * 512 + 256 + tid];
  __syncthreads();
  const int w = tid >> 6, l = tid & 63;
  for (int q = 0; q < 16; ++q) {
    const int k = w * 16 + q;
    const int n = idx[(size_t)t * 64 + k];
    const float* Wr = W_in + (size_t)n * 512;
    float s = 0.f;
#pragma unroll
    for (int j = 0; j < 8; ++j) s = fmaf(Wr[l + 64 * j], xs[l + 64 * j], s);
#pragma unroll
    for (int m = 1; m < 64; m <<= 1) s += __shfl_xor(s, m);
    if (l == 0) act[(size_t)t * 64 + k] = geluf(s);
  }
}

// ---------------- fused phi, MFMA version (one token per block) ----------------
// Phase A: h1 = gelu(LN1(nvphi[n] + act*pW1_row128)), bf16 -> h1s[pair][k]
// Phase B: pre2 = h1 @ pW2 + pb2 via mfma_f32_16x16x32_bf16 (pb2 folded into
//          the accumulator INIT — C operand of MFMA). pW2T staged in 4 chunks.
// Phase C: LN2 + pair-sum in C-fragment registers (col=lane&15, row=quad*4+reg).
// NOTE: __launch_bounds__(256,2) made the allocator cap at ~88 VGPRs -> 444MB
// scratch spill (R4). LDS (72KB) already pins occupancy at 2 blocks/CU, so
// (256,1) frees the allocator to keep acc+afr resident.
__global__ __launch_bounds__(256, 1) void k_phi(
    const float* __restrict__ nvphi, const float* __restrict__ pW1,
    const float* __restrict__ pln1_g, const float* __restrict__ pln1_b,
    const u16* __restrict__ pW2T, const float* __restrict__ pb2,
    const float* __restrict__ pln2_g, const float* __restrict__ pln2_b,
    const int* __restrict__ idx, const float* __restrict__ act,
    float* __restrict__ aggp) {
  __shared__ __align__(16) u16 h1s[64 * 264];  // pair-major, pad to 264
  __shared__ __align__(16) u16 Bs[64 * 264];   // staged pW2T rows
  __shared__ float aggbuf[4 * 256];
  __shared__ int idxs[64];
  __shared__ float acts[64];
  const int tid = threadIdx.x;
  const int t = blockIdx.x;
  const int w = tid >> 6, lane = tid & 63;
  const int q = lane >> 4, c = lane & 15;
  if (tid < 64) {
    idxs[tid] = idx[(size_t)t * 64 + tid];
    acts[tid] = act[(size_t)t * 64 + tid];
  }
  __syncthreads();
  // ---- Phase A: lane handles cols c*16..c*16+15 of pair w*16+rd*4+q ----
  {
    f32x4 w4[4], g1[4], b1[4];
#pragma unroll
    for (int j = 0; j < 4; ++j) {
      w4[j] = *(const f32x4*)&pW1[128 * 256 + c * 16 + j * 4];
      g1[j] = *(const f32x4*)&pln1_g[c * 16 + j * 4];
      b1[j] = *(const f32x4*)&pln1_b[c * 16 + j * 4];
    }
#pragma unroll 1
    for (int rd = 0; rd < 4; ++rd) {
      const int p = w * 16 + rd * 4 + q;
      const int n = idxs[p];
      const float av = acts[p];
      f32x4 v[4];
      float s = 0.f, s2 = 0.f;
#pragma unroll
      for (int j = 0; j < 4; ++j) {
        const f32x4 nv = *(const f32x4*)&nvphi[(size_t)n * 256 + c * 16 + j * 4];
#pragma unroll
        for (int u = 0; u < 4; ++u) {
          v[j][u] = nv[u] + av * w4[j][u];
          s += v[j][u];
          s2 = fmaf(v[j][u], v[j][u], s2);
        }
      }
#pragma unroll
      for (int m = 1; m < 16; m <<= 1) { s += __shfl_xor(s, m); s2 += __shfl_xor(s2, m); }
      const float mu = s * (1.f / 256.f);
      const float var = fmaxf(s2 * (1.f / 256.f) - mu * mu, 0.f);
      const float rstd = 1.f / sqrtf(var + 1e-5f);
      short8 lo, hi;
#pragma unroll
      for (int j = 0; j < 4; ++j)
#pragma unroll
        for (int u = 0; u < 4; ++u) {
          const float hv = geluf((v[j][u] - mu) * rstd * g1[j][u] + b1[j][u]);
          if (j < 2) lo[j * 4 + u] = (short)f2bf(hv);
          else       hi[(j - 2) * 4 + u] = (short)f2bf(hv);
        }
      *(short8*)&h1s[p * 264 + c * 16] = lo;
      *(short8*)&h1s[p * 264 + c * 16 + 8] = hi;
    }
  }
  __syncthreads();
  // ---- A-fragments: row m = w*16 + c, k = ks*32 + q*8 + j ----
  short8 afr[8];
#pragma unroll
  for (int ks = 0; ks < 8; ++ks)
    afr[ks] = *(const short8*)&h1s[(w * 16 + c) * 264 + ks * 32 + q * 8];
  // acc init = pb2 broadcast down rows (MFMA C-operand: D = A*B + C)
  f32x4 acc[16];
#pragma unroll
  for (int nt = 0; nt < 16; ++nt) {
    const float bz = pb2[nt * 16 + c];
    acc[nt] = (f32x4){bz, bz, bz, bz};
  }
  // ---- Phase B: 4 chunks of 64 N-rows ----
#pragma unroll 1
  for (int ch = 0; ch < 4; ++ch) {
    __syncthreads();
#pragma unroll
    for (int i = 0; i < 8; ++i) {
      const int cidx = i * 256 + tid;       // 0..2047 16B-chunks
      const int n = cidx >> 5, kc = cidx & 31;
      *(i32x4*)&Bs[n * 264 + kc * 8] =
          *(const i32x4*)&pW2T[(size_t)(ch * 64 + n) * 256 + kc * 8];
    }
    __syncthreads();
#pragma unroll
    for (int t4 = 0; t4 < 4; ++t4) {
      const int nt = ch * 4 + t4;
#pragma unroll
      for (int ks = 0; ks < 8; ++ks) {
        const short8 bfr = *(const short8*)&Bs[(t4 * 16 + c) * 264 + ks * 32 + q * 8];
        acc[nt] = __builtin_amdgcn_mfma_f32_16x16x32_bf16(afr[ks], bfr, acc[nt], 0, 0, 0);
      }
    }
  }
  // ---- Phase C: LN2 per pair (row = q*4+reg) + pair-sum ----
  float g2v[16], b2v[16];
#pragma unroll
  for (int nt = 0; nt < 16; ++nt) {
    g2v[nt] = pln2_g[nt * 16 + c];
    b2v[nt] = pln2_b[nt * 16 + c];
  }
  float aggl[16];
#pragma unroll
  for (int nt = 0; nt < 16; ++nt) aggl[nt] = 0.f;
#pragma unroll
  for (int reg = 0; reg < 4; ++reg) {
    float s = 0.f, s2 = 0.f;
#pragma unroll
    for (int nt = 0; nt < 16; ++nt) {
      const float vv = acc[nt][reg];
      s += vv;
      s2 = fmaf(vv, vv, s2);
    }
#pragma unroll
    for (int m = 1; m < 16; m <<= 1) { s += __shfl_xor(s, m); s2 += __shfl_xor(s2, m); }
    const float mu = s * (1.f / 256.f);
    const float var = fmaxf(s2 * (1.f / 256.f) - mu * mu, 0.f);
    const float rstd = 1.f / sqrtf(var + 1e-5f);
#pragma unroll
    for (int nt = 0; nt < 16; ++nt) {
      const float vv = acc[nt][reg];
      aggl[nt] += (vv - mu) * rstd * g2v[nt] + b2v[nt];
    }
  }
#pragma unroll
  for (int nt = 0; nt < 16; ++nt) {
    float vs = aggl[nt];
    vs += __shfl_xor(vs, 16);
    vs += __shfl_xor(vs, 32);
    if (q == 0) aggbuf[w * 256 + nt * 16 + c] = vs;
  }
  __syncthreads();
  aggp[(size_t)t * 256 + tid] =
      aggbuf[tid] + aggbuf[256 + tid] + aggbuf[512 + tid] + aggbuf[768 + tid];
}

// ---------------- r = LN(aggp[t]) over 256 ----------------
__global__ __launch_bounds__(256) void k_rln(const float* __restrict__ aggp,
                                             const float* __restrict__ g,
                                             const float* __restrict__ b,
                                             float* __restrict__ r) {
  __shared__ float red[8];
  const int t = blockIdx.x, tid = threadIdx.x;
  const float v = aggp[(size_t)t * 256 + tid];
  float s = v, s2 = v * v;
  waveRed2(s, s2);
  if ((tid & 63) == 0) { red[(tid >> 6) * 2] = s; red[(tid >> 6) * 2 + 1] = s2; }
  __syncthreads();
  s = red[0] + red[2] + red[4] + red[6];
  s2 = red[1] + red[3] + red[5] + red[7];
  const float mu = s * (1.f / 256.f);
  const float var = fmaxf(s2 * (1.f / 256.f) - mu * mu, 0.f);
  const float rstd = 1.f / sqrtf(var + 1e-5f);
  r[(size_t)t * 256 + tid] = (v - mu) * rstd * g[tid] + b[tid];
}

// ---------------- launch ----------------
extern "C" void kernel_launch(void* const* d_in, const int* in_sizes, int n_in,
                              void* d_out, int out_size, void* d_ws, size_t ws_size,
                              hipStream_t stream) {
  const float* x = (const float*)d_in[0];
  const float* W_in = (const float*)d_in[1];
  const float* nv = (const float*)d_in[2];
  const float* Wr1 = (const float*)d_in[3];
  const float* Wr2 = (const float*)d_in[4];
  const float* rn_g = (const float*)d_in[5];
  const float* rn_b = (const float*)d_in[6];
  const float* pW1 = (const float*)d_in[7];
  const float* pb1 = (const float*)d_in[8];
  const float* pln1_g = (const float*)d_in[9];
  const float* pln1_b = (const float*)d_in[10];
  const float* pW2 = (const float*)d_in[11];
  const float* pb2 = (const float*)d_in[12];
  const float* pln2_g = (const float*)d_in[13];
  const float* pln2_b = (const float*)d_in[14];
  const float* rln_g = (const float*)d_in[15];
  const float* rln_b = (const float*)d_in[16];
  const float* rW1 = (const float*)d_in[17];
  const float* rb1 = (const float*)d_in[18];
  const float* rW2 = (const float*)d_in[19];
  const float* rb2 = (const float*)d_in[20];
  float* out = (float*)d_out;
  const int T = in_sizes[0] / 512;  // 4096

  float* ws = (float*)d_ws;
  float* xln = ws;    ws += (size_t)T * 512;
  float* h = ws;      ws += (size_t)T * 512;
  float* scores = ws; ws += (size_t)T * 2048;
  float* nvphi = ws;  ws += (size_t)2048 * 256;
  float* actb = ws;   ws += (size_t)T * 64;
  float* aggp = ws;   ws += (size_t)T * 256;
  float* rbuf = ws;   ws += (size_t)T * 256;
  float* t1 = ws;     ws += (size_t)T * 512;
  int* idx = (int*)ws; ws += (size_t)T * 64;
  u16* pW2T = (u16*)ws;

  k_nvphi<<<2048, 256, 0, stream>>>(nv, pW1, pb1, nvphi);
  k_pw2t<<<256, 256, 0, stream>>>(pW2, pW2T);
  k_ln512<<<T, 256, 0, stream>>>(x, rn_g, rn_b, xln);
  gemm_bt<true><<<dim3(512 / 64, T / 64), 256, 0, stream>>>(xln, Wr1, h, T, 512, 512);
  gemm_bt<false><<<dim3(2048 / 64, T / 64), 256, 0, stream>>>(h, Wr2, scores, T, 2048, 512);
  k_topk<<<T, 256, 0, stream>>>(scores, idx);
  k_act<<<T, 256, 0, stream>>>(x, W_in, idx, actb);
  k_phi<<<T, 256, 0, stream>>>(nvphi, pW1, pln1_g, pln1_b, pW2T, pb2, pln2_g,
                               pln2_b, idx, actb, aggp);
  k_rln<<<T, 256, 0, stream>>>(aggp, rln_g, rln_b, rbuf);
  gemm_bn<true><<<dim3(512 / 64, T / 64), 256, 0, stream>>>(rbuf, rW1, rb1, t1, T, 512, 256);
  gemm_bn<false><<<dim3(512 / 64, T / 64), 256, 0, stream>>>(t1, rW2, rb2, out, T, 512, 512);
}

// Round 6
// 558.306 us; speedup vs baseline: 1.1691x; 1.1691x over previous
//
#include <hip/hip_runtime.h>
#include <cstdint>
#include <cstddef>

typedef unsigned short u16;
typedef float f32x4 __attribute__((ext_vector_type(4)));
typedef short short8 __attribute__((ext_vector_type(8)));
typedef int i32x4 __attribute__((ext_vector_type(4)));

// ---------------- helpers ----------------

__device__ __forceinline__ float geluf(float v) {
  return 0.5f * v * (1.0f + erff(v * 0.70710678118654752440f));
}

__device__ __forceinline__ u16 f2bf(float f) {  // RNE fp32 -> bf16 bits
  unsigned u = __float_as_uint(f);
  u = (u + 0x7FFFu + ((u >> 16) & 1u)) >> 16;
  return (u16)u;
}

__device__ __forceinline__ void waveRed2(float& s, float& s2) {
#pragma unroll
  for (int m = 1; m < 64; m <<= 1) {
    s += __shfl_xor(s, m);
    s2 += __shfl_xor(s2, m);
  }
}

// ---------------- LN over 512 (router input) ----------------
__global__ __launch_bounds__(256) void k_ln512(const float* __restrict__ x,
                                               const float* __restrict__ g,
                                               const float* __restrict__ b,
                                               float* __restrict__ out) {
  __shared__ float red[8];
  const int t = blockIdx.x, tid = threadIdx.x;
  const float v0 = x[(size_t)t * 512 + tid];
  const float v1 = x[(size_t)t * 512 + 256 + tid];
  float s = v0 + v1, s2 = v0 * v0 + v1 * v1;
  waveRed2(s, s2);
  if ((tid & 63) == 0) { red[(tid >> 6) * 2] = s; red[(tid >> 6) * 2 + 1] = s2; }
  __syncthreads();
  s = red[0] + red[2] + red[4] + red[6];
  s2 = red[1] + red[3] + red[5] + red[7];
  const float mu = s * (1.f / 512.f);
  const float var = fmaxf(s2 * (1.f / 512.f) - mu * mu, 0.f);
  const float rstd = 1.f / sqrtf(var + 1e-5f);
  out[(size_t)t * 512 + tid] = (v0 - mu) * rstd * g[tid] + b[tid];
  out[(size_t)t * 512 + 256 + tid] = (v1 - mu) * rstd * g[tid + 256] + b[tid + 256];
}

// ---------------- nvphi precompute: [2048,256] = nv@pW1[:128] + pb1 ----------------
__global__ __launch_bounds__(256) void k_nvphi(const float* __restrict__ nv,
                                               const float* __restrict__ pW1,
                                               const float* __restrict__ pb1,
                                               float* __restrict__ nvphi) {
  __shared__ float nvs[128];
  const int n = blockIdx.x, tid = threadIdx.x;
  if (tid < 128) nvs[tid] = nv[n * 128 + tid];
  __syncthreads();
  float s = pb1[tid];
#pragma unroll 4
  for (int i = 0; i < 128; ++i) s = fmaf(nvs[i], pW1[i * 256 + tid], s);
  nvphi[n * 256 + tid] = s;
}

// ---------------- pW2T[n][k] = bf16(pW2[k][n]) ----------------
__global__ __launch_bounds__(256) void k_pw2t(const float* __restrict__ pW2,
                                              u16* __restrict__ pW2T) {
  const int n = blockIdx.x, k = threadIdx.x;
  pW2T[n * 256 + k] = f2bf(pW2[k * 256 + n]);
}

// ---------------- tiled fp32 GEMM, C = act(A[M,K] @ B[N,K]^T) ----------------
template <bool GELU_>
__global__ __launch_bounds__(256) void gemm_bt(const float* __restrict__ A,
                                               const float* __restrict__ B,
                                               float* __restrict__ C, int M, int N,
                                               int K) {
  __shared__ float As[16][68];
  __shared__ float Bs[16][68];
  const int tid = threadIdx.x;
  const int tn = tid & 15, tm = tid >> 4;
  const int m0 = blockIdx.y * 64, n0 = blockIdx.x * 64;
  const int lr = tid >> 2, lk = (tid & 3) << 2;
  float acc[4][4] = {};
  for (int k0 = 0; k0 < K; k0 += 16) {
    const float4 av = *(const float4*)&A[(size_t)(m0 + lr) * K + k0 + lk];
    const float4 bv = *(const float4*)&B[(size_t)(n0 + lr) * K + k0 + lk];
    As[lk + 0][lr] = av.x; As[lk + 1][lr] = av.y; As[lk + 2][lr] = av.z; As[lk + 3][lr] = av.w;
    Bs[lk + 0][lr] = bv.x; Bs[lk + 1][lr] = bv.y; Bs[lk + 2][lr] = bv.z; Bs[lk + 3][lr] = bv.w;
    __syncthreads();
#pragma unroll
    for (int k = 0; k < 16; ++k) {
      float a[4], b[4];
      *(float4*)a = *(const float4*)&As[k][tm * 4];
      *(float4*)b = *(const float4*)&Bs[k][tn * 4];
#pragma unroll
      for (int i = 0; i < 4; ++i)
#pragma unroll
        for (int j = 0; j < 4; ++j) acc[i][j] = fmaf(a[i], b[j], acc[i][j]);
    }
    __syncthreads();
  }
#pragma unroll
  for (int i = 0; i < 4; ++i) {
    float4 v;
    float* vp = (float*)&v;
#pragma unroll
    for (int j = 0; j < 4; ++j) {
      float xv = acc[i][j];
      if (GELU_) xv = geluf(xv);
      vp[j] = xv;
    }
    *(float4*)&C[(size_t)(m0 + tm * 4 + i) * N + n0 + tn * 4] = v;
  }
}

// ---------------- tiled fp32 GEMM, C = act(A[M,K] @ B[K,N] + bias) ----------------
template <bool GELU_>
__global__ __launch_bounds__(256) void gemm_bn(const float* __restrict__ A,
                                               const float* __restrict__ B,
                                               const float* __restrict__ bias,
                                               float* __restrict__ C, int M, int N,
                                               int K) {
  __shared__ float As[16][68];
  __shared__ float Bs[16][68];
  const int tid = threadIdx.x;
  const int tn = tid & 15, tm = tid >> 4;
  const int m0 = blockIdx.y * 64, n0 = blockIdx.x * 64;
  const int lr = tid >> 2, lk = (tid & 3) << 2;
  const int bk = tid >> 4, bn = (tid & 15) << 2;
  float acc[4][4] = {};
  for (int k0 = 0; k0 < K; k0 += 16) {
    const float4 av = *(const float4*)&A[(size_t)(m0 + lr) * K + k0 + lk];
    const float4 bv = *(const float4*)&B[(size_t)(k0 + bk) * N + n0 + bn];
    As[lk + 0][lr] = av.x; As[lk + 1][lr] = av.y; As[lk + 2][lr] = av.z; As[lk + 3][lr] = av.w;
    *(float4*)&Bs[bk][bn] = bv;
    __syncthreads();
#pragma unroll
    for (int k = 0; k < 16; ++k) {
      float a[4], b[4];
      *(float4*)a = *(const float4*)&As[k][tm * 4];
      *(float4*)b = *(const float4*)&Bs[k][tn * 4];
#pragma unroll
      for (int i = 0; i < 4; ++i)
#pragma unroll
        for (int j = 0; j < 4; ++j) acc[i][j] = fmaf(a[i], b[j], acc[i][j]);
    }
    __syncthreads();
  }
#pragma unroll
  for (int i = 0; i < 4; ++i) {
    float4 v;
    float* vp = (float*)&v;
#pragma unroll
    for (int j = 0; j < 4; ++j) {
      float xv = acc[i][j] + bias[n0 + tn * 4 + j];
      if (GELU_) xv = geluf(xv);
      vp[j] = xv;
    }
    *(float4*)&C[(size_t)(m0 + tm * 4 + i) * N + n0 + tn * 4] = v;
  }
}

// ---------------- top-64 of 2048 scores per token ----------------
__global__ __launch_bounds__(256) void k_topk(const float* __restrict__ scores,
                                              int* __restrict__ idxout) {
  __shared__ int redc[4];
  __shared__ unsigned cg_cnt, ec;
  __shared__ int eqbuf[64];
  const int t = blockIdx.x, tid = threadIdx.x;
  unsigned key[8];
#pragma unroll
  for (int j = 0; j < 8; ++j) {
    const unsigned u = __float_as_uint(scores[(size_t)t * 2048 + tid + 256 * j]);
    key[j] = (u & 0x80000000u) ? ~u : (u | 0x80000000u);
  }
  unsigned lo = 0u, hi = 0xFFFFFFFFu;
  while (lo < hi) {
    const unsigned mid = (unsigned)(((unsigned long long)lo + hi + 1ull) >> 1);
    int c = 0;
#pragma unroll
    for (int j = 0; j < 8; ++j) c += (key[j] >= mid);
#pragma unroll
    for (int m = 1; m < 64; m <<= 1) c += __shfl_xor(c, m);
    if ((tid & 63) == 0) redc[tid >> 6] = c;
    __syncthreads();
    const int total = redc[0] + redc[1] + redc[2] + redc[3];
    __syncthreads();
    if (total >= 64) lo = mid; else hi = mid - 1;
  }
  if (tid == 0) { cg_cnt = 0u; ec = 0u; }
  __syncthreads();
#pragma unroll
  for (int j = 0; j < 8; ++j) {
    if (key[j] > lo) {
      const unsigned pos = atomicAdd(&cg_cnt, 1u);
      idxout[(size_t)t * 64 + pos] = tid + 256 * j;
    } else if (key[j] == lo) {
      const unsigned e = atomicAdd(&ec, 1u);
      if (e < 64u) eqbuf[e] = tid + 256 * j;
    }
  }
  __syncthreads();
  if (tid == 0) {
    const int cg = (int)cg_cnt;
    int ne = (int)ec; if (ne > 64) ne = 64;
    const int need = 64 - cg;
    for (int i = 1; i < ne; ++i) {
      const int v = eqbuf[i];
      int j = i - 1;
      while (j >= 0 && eqbuf[j] > v) { eqbuf[j + 1] = eqbuf[j]; --j; }
      eqbuf[j + 1] = v;
    }
    for (int i = 0; i < need; ++i) idxout[(size_t)t * 64 + cg + i] = eqbuf[i];
  }
}

// ---------------- act[t][k] = gelu(dot(x[t], W_in[idx[t][k]])) ----------------
__global__ __launch_bounds__(256) void k_act(const float* __restrict__ x,
                                             const float* __restrict__ W_in,
                                             const int* __restrict__ idx,
                                             float* __restrict__ act) {
  __shared__ float xs[512];
  const int t = blockIdx.x, tid = threadIdx.x;
  xs[tid] = x[(size_t)t * 512 + tid];
  xs[tid + 256] = x[(size_t)t * 512 + 256 + tid];
  __syncthreads();
  const int w = tid >> 6, l = tid & 63;
  for (int q = 0; q < 16; ++q) {
    const int k = w * 16 + q;
    const int n = idx[(size_t)t * 64 + k];
    const float* Wr = W_in + (size_t)n * 512;
    float s = 0.f;
#pragma unroll
    for (int j = 0; j < 8; ++j) s = fmaf(Wr[l + 64 * j], xs[l + 64 * j], s);
#pragma unroll
    for (int m = 1; m < 64; m <<= 1) s += __shfl_xor(s, m);
    if (l == 0) act[(size_t)t * 64 + k] = geluf(s);
  }
}

// ---------------- fused phi, MFMA version (one token per block) ----------------
// Phase A: h1 = gelu(LN1(nvphi[n] + act*pW1_row128)), bf16 -> h1s[pair][k]
// Phase B: pre2 = h1 @ pW2 + pb2 via mfma_f32_16x16x32_bf16 (pb2 folded into
//          the accumulator INIT). pW2T staged in 4 chunks of 64 N-rows.
//          The chunk loop is FULLY UNROLLED: acc[ch*4+t4] with runtime ch was
//          dynamic register indexing -> whole acc[16] array spilled to scratch
//          (450MB WRITE_SIZE in R4/R5). All indices must be compile-time.
// Phase C: LN2 + pair-sum in C-fragment registers (col=lane&15, row=quad*4+reg).
__global__ __launch_bounds__(256, 1) void k_phi(
    const float* __restrict__ nvphi, const float* __restrict__ pW1,
    const float* __restrict__ pln1_g, const float* __restrict__ pln1_b,
    const u16* __restrict__ pW2T, const float* __restrict__ pb2,
    const float* __restrict__ pln2_g, const float* __restrict__ pln2_b,
    const int* __restrict__ idx, const float* __restrict__ act,
    float* __restrict__ aggp) {
  __shared__ __align__(16) u16 h1s[64 * 264];  // pair-major, pad to 264
  __shared__ __align__(16) u16 Bs[64 * 264];   // staged pW2T rows
  __shared__ float aggbuf[4 * 256];
  __shared__ int idxs[64];
  __shared__ float acts[64];
  const int tid = threadIdx.x;
  const int t = blockIdx.x;
  const int w = tid >> 6, lane = tid & 63;
  const int q = lane >> 4, c = lane & 15;
  if (tid < 64) {
    idxs[tid] = idx[(size_t)t * 64 + tid];
    acts[tid] = act[(size_t)t * 64 + tid];
  }
  __syncthreads();
  // ---- Phase A: lane handles cols c*16..c*16+15 of pair w*16+rd*4+q ----
  {
    f32x4 w4[4], g1[4], b1[4];
#pragma unroll
    for (int j = 0; j < 4; ++j) {
      w4[j] = *(const f32x4*)&pW1[128 * 256 + c * 16 + j * 4];
      g1[j] = *(const f32x4*)&pln1_g[c * 16 + j * 4];
      b1[j] = *(const f32x4*)&pln1_b[c * 16 + j * 4];
    }
#pragma unroll 1
    for (int rd = 0; rd < 4; ++rd) {
      const int p = w * 16 + rd * 4 + q;
      const int n = idxs[p];
      const float av = acts[p];
      f32x4 v[4];
      float s = 0.f, s2 = 0.f;
#pragma unroll
      for (int j = 0; j < 4; ++j) {
        const f32x4 nv = *(const f32x4*)&nvphi[(size_t)n * 256 + c * 16 + j * 4];
#pragma unroll
        for (int u = 0; u < 4; ++u) {
          v[j][u] = nv[u] + av * w4[j][u];
          s += v[j][u];
          s2 = fmaf(v[j][u], v[j][u], s2);
        }
      }
#pragma unroll
      for (int m = 1; m < 16; m <<= 1) { s += __shfl_xor(s, m); s2 += __shfl_xor(s2, m); }
      const float mu = s * (1.f / 256.f);
      const float var = fmaxf(s2 * (1.f / 256.f) - mu * mu, 0.f);
      const float rstd = 1.f / sqrtf(var + 1e-5f);
      short8 lo, hi;
#pragma unroll
      for (int j = 0; j < 4; ++j)
#pragma unroll
        for (int u = 0; u < 4; ++u) {
          const float hv = geluf((v[j][u] - mu) * rstd * g1[j][u] + b1[j][u]);
          if (j < 2) lo[j * 4 + u] = (short)f2bf(hv);
          else       hi[(j - 2) * 4 + u] = (short)f2bf(hv);
        }
      *(short8*)&h1s[p * 264 + c * 16] = lo;
      *(short8*)&h1s[p * 264 + c * 16 + 8] = hi;
    }
  }
  __syncthreads();
  // ---- A-fragments: row m = w*16 + c, k = ks*32 + q*8 + j ----
  short8 afr[8];
#pragma unroll
  for (int ks = 0; ks < 8; ++ks)
    afr[ks] = *(const short8*)&h1s[(w * 16 + c) * 264 + ks * 32 + q * 8];
  // acc init = pb2 broadcast down rows (MFMA C-operand: D = A*B + C)
  f32x4 acc[16];
#pragma unroll
  for (int nt = 0; nt < 16; ++nt) {
    const float bz = pb2[nt * 16 + c];
    acc[nt] = (f32x4){bz, bz, bz, bz};
  }
  // ---- Phase B: 4 chunks of 64 N-rows; ch FULLY unrolled (see note) ----
#pragma unroll
  for (int ch = 0; ch < 4; ++ch) {
    __syncthreads();
#pragma unroll
    for (int i = 0; i < 8; ++i) {
      const int cidx = i * 256 + tid;       // 0..2047 16B-chunks
      const int n = cidx >> 5, kc = cidx & 31;
      *(i32x4*)&Bs[n * 264 + kc * 8] =
          *(const i32x4*)&pW2T[(size_t)(ch * 64 + n) * 256 + kc * 8];
    }
    __syncthreads();
#pragma unroll
    for (int t4 = 0; t4 < 4; ++t4) {
      const int nt = ch * 4 + t4;
#pragma unroll
      for (int ks = 0; ks < 8; ++ks) {
        const short8 bfr = *(const short8*)&Bs[(t4 * 16 + c) * 264 + ks * 32 + q * 8];
        acc[nt] = __builtin_amdgcn_mfma_f32_16x16x32_bf16(afr[ks], bfr, acc[nt], 0, 0, 0);
      }
    }
  }
  // ---- Phase C: LN2 per pair (row = q*4+reg) + pair-sum ----
  float g2v[16], b2v[16];
#pragma unroll
  for (int nt = 0; nt < 16; ++nt) {
    g2v[nt] = pln2_g[nt * 16 + c];
    b2v[nt] = pln2_b[nt * 16 + c];
  }
  float aggl[16];
#pragma unroll
  for (int nt = 0; nt < 16; ++nt) aggl[nt] = 0.f;
#pragma unroll
  for (int reg = 0; reg < 4; ++reg) {
    float s = 0.f, s2 = 0.f;
#pragma unroll
    for (int nt = 0; nt < 16; ++nt) {
      const float vv = acc[nt][reg];
      s += vv;
      s2 = fmaf(vv, vv, s2);
    }
#pragma unroll
    for (int m = 1; m < 16; m <<= 1) { s += __shfl_xor(s, m); s2 += __shfl_xor(s2, m); }
    const float mu = s * (1.f / 256.f);
    const float var = fmaxf(s2 * (1.f / 256.f) - mu * mu, 0.f);
    const float rstd = 1.f / sqrtf(var + 1e-5f);
#pragma unroll
    for (int nt = 0; nt < 16; ++nt) {
      const float vv = acc[nt][reg];
      aggl[nt] += (vv - mu) * rstd * g2v[nt] + b2v[nt];
    }
  }
#pragma unroll
  for (int nt = 0; nt < 16; ++nt) {
    float vs = aggl[nt];
    vs += __shfl_xor(vs, 16);
    vs += __shfl_xor(vs, 32);
    if (q == 0) aggbuf[w * 256 + nt * 16 + c] = vs;
  }
  __syncthreads();
  aggp[(size_t)t * 256 + tid] =
      aggbuf[tid] + aggbuf[256 + tid] + aggbuf[512 + tid] + aggbuf[768 + tid];
}

// ---------------- r = LN(aggp[t]) over 256 ----------------
__global__ __launch_bounds__(256) void k_rln(const float* __restrict__ aggp,
                                             const float* __restrict__ g,
                                             const float* __restrict__ b,
                                             float* __restrict__ r) {
  __shared__ float red[8];
  const int t = blockIdx.x, tid = threadIdx.x;
  const float v = aggp[(size_t)t * 256 + tid];
  float s = v, s2 = v * v;
  waveRed2(s, s2);
  if ((tid & 63) == 0) { red[(tid >> 6) * 2] = s; red[(tid >> 6) * 2 + 1] = s2; }
  __syncthreads();
  s = red[0] + red[2] + red[4] + red[6];
  s2 = red[1] + red[3] + red[5] + red[7];
  const float mu = s * (1.f / 256.f);
  const float var = fmaxf(s2 * (1.f / 256.f) - mu * mu, 0.f);
  const float rstd = 1.f / sqrtf(var + 1e-5f);
  r[(size_t)t * 256 + tid] = (v - mu) * rstd * g[tid] + b[tid];
}

// ---------------- launch ----------------
extern "C" void kernel_launch(void* const* d_in, const int* in_sizes, int n_in,
                              void* d_out, int out_size, void* d_ws, size_t ws_size,
                              hipStream_t stream) {
  const float* x = (const float*)d_in[0];
  const float* W_in = (const float*)d_in[1];
  const float* nv = (const float*)d_in[2];
  const float* Wr1 = (const float*)d_in[3];
  const float* Wr2 = (const float*)d_in[4];
  const float* rn_g = (const float*)d_in[5];
  const float* rn_b = (const float*)d_in[6];
  const float* pW1 = (const float*)d_in[7];
  const float* pb1 = (const float*)d_in[8];
  const float* pln1_g = (const float*)d_in[9];
  const float* pln1_b = (const float*)d_in[10];
  const float* pW2 = (const float*)d_in[11];
  const float* pb2 = (const float*)d_in[12];
  const float* pln2_g = (const float*)d_in[13];
  const float* pln2_b = (const float*)d_in[14];
  const float* rln_g = (const float*)d_in[15];
  const float* rln_b = (const float*)d_in[16];
  const float* rW1 = (const float*)d_in[17];
  const float* rb1 = (const float*)d_in[18];
  const float* rW2 = (const float*)d_in[19];
  const float* rb2 = (const float*)d_in[20];
  float* out = (float*)d_out;
  const int T = in_sizes[0] / 512;  // 4096

  float* ws = (float*)d_ws;
  float* xln = ws;    ws += (size_t)T * 512;
  float* h = ws;      ws += (size_t)T * 512;
  float* scores = ws; ws += (size_t)T * 2048;
  float* nvphi = ws;  ws += (size_t)2048 * 256;
  float* actb = ws;   ws += (size_t)T * 64;
  float* aggp = ws;   ws += (size_t)T * 256;
  float* rbuf = ws;   ws += (size_t)T * 256;
  float* t1 = ws;     ws += (size_t)T * 512;
  int* idx = (int*)ws; ws += (size_t)T * 64;
  u16* pW2T = (u16*)ws;

  k_nvphi<<<2048, 256, 0, stream>>>(nv, pW1, pb1, nvphi);
  k_pw2t<<<256, 256, 0, stream>>>(pW2, pW2T);
  k_ln512<<<T, 256, 0, stream>>>(x, rn_g, rn_b, xln);
  gemm_bt<true><<<dim3(512 / 64, T / 64), 256, 0, stream>>>(xln, Wr1, h, T, 512, 512);
  gemm_bt<false><<<dim3(2048 / 64, T / 64), 256, 0, stream>>>(h, Wr2, scores, T, 2048, 512);
  k_topk<<<T, 256, 0, stream>>>(scores, idx);
  k_act<<<T, 256, 0, stream>>>(x, W_in, idx, actb);
  k_phi<<<T, 256, 0, stream>>>(nvphi, pW1, pln1_g, pln1_b, pW2T, pb2, pln2_g,
                               pln2_b, idx, actb, aggp);
  k_rln<<<T, 256, 0, stream>>>(aggp, rln_g, rln_b, rbuf);
  gemm_bn<true><<<dim3(512 / 64, T / 64), 256, 0, stream>>>(rbuf, rW1, rb1, t1, T, 512, 256);
  gemm_bn<false><<<dim3(512 / 64, T / 64), 256, 0, stream>>>(t1, rW2, rb2, out, T, 512, 512);
}